// Round 7
// baseline (57.446 us; speedup 1.0000x reference)
//
#include <hip/hip_runtime.h>

#define LSEQ 8192
#define CH   256

typedef __attribute__((ext_vector_type(8)))  short short8;
typedef __attribute__((ext_vector_type(4)))  short short4v;
typedef __attribute__((ext_vector_type(16))) float f32x16;
typedef unsigned int u32;

__device__ inline short f2bf(float f) {
  union { float f; unsigned u; } v; v.f = f;
  unsigned r = v.u + 0x7fffu + ((v.u >> 16) & 1u);
  return (short)(r >> 16);
}
__device__ inline short8 cvt8(float4 a, float4 b) {
  short8 v;
  v[0] = f2bf(a.x); v[1] = f2bf(a.y); v[2] = f2bf(a.z); v[3] = f2bf(a.w);
  v[4] = f2bf(b.x); v[5] = f2bf(b.y); v[6] = f2bf(b.z); v[7] = f2bf(b.w);
  return v;
}
__device__ inline f32x16 mfma32(short8 a, short8 b, f32x16 c) {
  return __builtin_amdgcn_mfma_f32_32x32x16_bf16(a, b, c, 0, 0, 0);
}
// async global -> LDS, 16B per lane; dest = wave-uniform base (+ lane*16 by HW)
__device__ __forceinline__ void gload16(const void* g, void* l) {
  __builtin_amdgcn_global_load_lds(
      (const __attribute__((address_space(1))) u32*)g,
      (__attribute__((address_space(3))) u32*)l, 16, 0, 0);
}

// ---------------------------------------------------------------------------
// prep: blocks 0..127  -> xb = bf16(x) (64 rows each) + sx col-sum atomics
//       block 128      -> Wkb = bf16(Wk)
//       block 129      -> Wvb = bf16(Wv)
// ---------------------------------------------------------------------------
__global__ __launch_bounds__(256) void prep_kernel(
    const float* __restrict__ x,
    const float* __restrict__ Wk, const float* __restrict__ Wv,
    short* __restrict__ xb, short* __restrict__ Wkb, short* __restrict__ Wvb,
    float* __restrict__ sx)
{
  const int b = blockIdx.x, tid = threadIdx.x;
  if (b < 128) {
    __shared__ float red[256][8];
    const int r0 = b * 64;
    float part[8] = {};
#pragma unroll
    for (int i = 0; i < 8; ++i) {
      int g = i * 256 + tid;
      int row = r0 + (g >> 5), c8 = g & 31;      // c8 = tid&31 (constant/thread)
      const float4* src = (const float4*)(x + (size_t)row * CH + c8 * 8);
      float4 a = src[0], c = src[1];
      part[0] += a.x; part[1] += a.y; part[2] += a.z; part[3] += a.w;
      part[4] += c.x; part[5] += c.y; part[6] += c.z; part[7] += c.w;
      *(short8*)(xb + (size_t)row * CH + c8 * 8) = cvt8(a, c);
    }
#pragma unroll
    for (int j = 0; j < 8; ++j) red[tid][j] = part[j];
    __syncthreads();
    // col c = tid: owners are threads (c>>3) + 32k, slot c&7
    float s = 0.f;
#pragma unroll
    for (int k = 0; k < 8; ++k) s += red[(tid >> 3) + 32 * k][tid & 7];
    atomicAdd(&sx[tid], s);
  } else {
    const float* src = (b == 128) ? Wk : Wv;
    short* dst = (b == 128) ? Wkb : Wvb;
#pragma unroll
    for (int i = 0; i < 32; ++i) {
      int g = i * 256 + tid;                     // 8192 chunks of 8 elems
      const float4* s4 = (const float4*)(src + (size_t)g * 8);
      *(short8*)(dst + (size_t)g * 8) = cvt8(s4[0], s4[1]);
    }
  }
}

// ---------------------------------------------------------------------------
// kv: y = x @ W^T + b for W in {Wk, Wv}; outputs transposed bf16
//   blockIdx.y: 0 -> KTb[c][row], 1 -> VTb[d][row]
// W tile [128 outcols][256] bf16 staged via gload16 (src pre-swizzle ^(rr&31)).
// ---------------------------------------------------------------------------
__global__ __launch_bounds__(256) void kv_kernel(
    const short* __restrict__ xb,
    const short* __restrict__ Wkb, const short* __restrict__ Wvb,
    const float* __restrict__ bk, const float* __restrict__ bv,
    short* __restrict__ KTb, short* __restrict__ VTb)
{
  const int m = blockIdx.y;
  const short* Wb = m ? Wvb : Wkb;
  const float* bp = m ? bv : bk;
  short* dst = m ? VTb : KTb;
  const int rb = blockIdx.x >> 1, cb = blockIdx.x & 1;
  const int row0 = rb * 128, col0 = cb * 128;

  __shared__ __align__(16) short wt[128 * 256];   // 64KB

  const int tid = threadIdx.x, wid = tid >> 6, lane = tid & 63;
  const int l31 = lane & 31, hi = lane >> 5;

#pragma unroll
  for (int i = 0; i < 16; ++i) {
    int g = i * 256 + tid, rr = g >> 5, p = g & 31;
    gload16(Wb + (size_t)(col0 + rr) * CH + (p ^ (rr & 31)) * 8,
            &wt[(i * 256 + wid * 64) * 8]);
  }
  __syncthreads();

  const int wrow0 = row0 + wid * 32;
  f32x16 acc[4] = {};
#pragma unroll
  for (int kd = 0; kd < 16; ++kd) {
    short8 af = *(const short8*)(xb + (size_t)(wrow0 + l31) * CH + kd * 16 + hi * 8);
#pragma unroll
    for (int nf = 0; nf < 4; ++nf) {
      int r = nf * 32 + l31;
      short8 bf = *(const short8*)(&wt[r * 256 + (((kd * 2 + hi) ^ (r & 31)) * 8)]);
      acc[nf] = mfma32(af, bf, acc[nf]);
    }
  }

  // D: col = outdim (l31+32nf), row = wrow0 + (r&3)+8*(r>>2)+4*hi; store ^T
#pragma unroll
  for (int nf = 0; nf < 4; ++nf) {
    int col = col0 + nf * 32 + l31;
    float bias = bp[col];
#pragma unroll
    for (int g = 0; g < 4; ++g) {
      short4v v;
#pragma unroll
      for (int r2 = 0; r2 < 4; ++r2) v[r2] = f2bf(acc[nf][g * 4 + r2] + bias);
      *(short4v*)(&dst[(size_t)col * LSEQ + wrow0 + g * 8 + hi * 4]) = v;
    }
  }
}

// ---------------------------------------------------------------------------
// gram: MT[d][c] = sum_j V[j][d] K[j][c]  (= V^T K), fp32 atomic accum.
// (unchanged, verified round 6)
// ---------------------------------------------------------------------------
__global__ __launch_bounds__(256) void gram_kernel(
    const short* __restrict__ VTb, const short* __restrict__ KTb,
    float* __restrict__ MT)
{
  __shared__ __align__(16) short at[128 * 128];
  __shared__ __align__(16) short bt[128 * 128];

  const int tile = blockIdx.x & 3, split = blockIdx.x >> 2;
  const int d0 = (tile >> 1) * 128, c0 = (tile & 1) * 128;
  const int tid = threadIdx.x, wid = tid >> 6, lane = tid & 63;
  const int l31 = lane & 31, hi = lane >> 5;
  const int wr = wid >> 1, wc = wid & 1;

  f32x16 acc[2][2] = {};

#pragma unroll
  for (int jj = 0; jj < 2; ++jj) {
    const int j0 = split * 256 + jj * 128;
    __syncthreads();
#pragma unroll
    for (int i = 0; i < 8; ++i) {
      int g = i * 256 + tid, rr = g >> 4, p = g & 15;
      gload16(VTb + (size_t)(d0 + rr) * LSEQ + j0 + ((p ^ (rr & 15)) * 8),
              &at[(i * 256 + wid * 64) * 8]);
    }
#pragma unroll
    for (int i = 0; i < 8; ++i) {
      int g = i * 256 + tid, rr = g >> 4, p = g & 15;
      gload16(KTb + (size_t)(c0 + rr) * LSEQ + j0 + ((p ^ (rr & 15)) * 8),
              &bt[(i * 256 + wid * 64) * 8]);
    }
    __syncthreads();

#pragma unroll
    for (int kd = 0; kd < 8; ++kd) {
      int ra0 = wr * 64 + l31, ra1 = ra0 + 32;
      int rb0 = wc * 64 + l31, rb1 = rb0 + 32;
      int ck = kd * 2 + hi;
      short8 a0 = *(const short8*)(&at[ra0 * 128 + ((ck ^ (ra0 & 15)) * 8)]);
      short8 a1 = *(const short8*)(&at[ra1 * 128 + ((ck ^ (ra1 & 15)) * 8)]);
      short8 b0 = *(const short8*)(&bt[rb0 * 128 + ((ck ^ (rb0 & 15)) * 8)]);
      short8 b1 = *(const short8*)(&bt[rb1 * 128 + ((ck ^ (rb1 & 15)) * 8)]);
      acc[0][0] = mfma32(a0, b0, acc[0][0]);
      acc[0][1] = mfma32(a0, b1, acc[0][1]);
      acc[1][0] = mfma32(a1, b0, acc[1][0]);
      acc[1][1] = mfma32(a1, b1, acc[1][1]);
    }
  }

#pragma unroll
  for (int mt = 0; mt < 2; ++mt)
#pragma unroll
    for (int nt = 0; nt < 2; ++nt) {
      int ccol = c0 + wc * 64 + nt * 32 + l31;
#pragma unroll
      for (int r = 0; r < 16; ++r) {
        int drow = d0 + wr * 64 + mt * 32 + (r & 3) + 8 * (r >> 2) + 4 * hi;
        atomicAdd(&MT[drow * CH + ccol], acc[mt][nt][r]);
      }
    }
}

// ---------------------------------------------------------------------------
// small: blocks 0-3 -> HT = MT . Wq  (HT[d][e] = sum_c MT[d][c] Wq[c][e]),
//        A = MT fp32 rows (cvt), B = Wq^T via in-LDS transpose. bf16 out.
//        block 4 -> sq = Wq sx + L bq ; 5 -> sk = Wk sx + L bk ;
//        block 6 -> cv = Wv sx + L bv ; 7 -> r = MT bq.
// ---------------------------------------------------------------------------
__global__ __launch_bounds__(256) void small_kernel(
    const float* __restrict__ MT, const float* __restrict__ Wq,
    const float* __restrict__ Wk, const float* __restrict__ Wv,
    const float* __restrict__ bq, const float* __restrict__ bk,
    const float* __restrict__ bv, const float* __restrict__ sx,
    short* __restrict__ HTb, float* __restrict__ sq, float* __restrict__ sk,
    float* __restrict__ cv, float* __restrict__ r)
{
  __shared__ __align__(16) short wt[128 * 256];   // 64KB
  const int b = blockIdx.x, tid = threadIdx.x;

  if (b < 4) {
    const int rb = b >> 1, cb = b & 1;
    const int row0 = rb * 128, col0 = cb * 128;   // row0: d, col0: e
    // transpose-stage: wt[e - col0][c] = Wq[c][e], swizzled chunks ^(row&31)
#pragma unroll
    for (int i = 0; i < 32; ++i) {
      int g = i * 256 + tid;
      int c = g & 255, ep = g >> 8;               // ep 0..31
      float4 v4 = *(const float4*)(Wq + (size_t)c * CH + col0 + ep * 4);
#pragma unroll
      for (int j = 0; j < 4; ++j) {
        int rr = ep * 4 + j;
        wt[rr * 256 + (((c >> 3) ^ (rr & 31)) * 8) + (c & 7)] =
            f2bf(j == 0 ? v4.x : (j == 1 ? v4.y : (j == 2 ? v4.z : v4.w)));
      }
    }
    __syncthreads();

    const int wid = tid >> 6, lane = tid & 63;
    const int l31 = lane & 31, hi = lane >> 5;
    const int wrow0 = row0 + wid * 32;

    f32x16 acc[4] = {};
#pragma unroll
    for (int kd = 0; kd < 16; ++kd) {
      const float4* ms = (const float4*)(MT + (size_t)(wrow0 + l31) * CH + kd * 16 + hi * 8);
      short8 af = cvt8(ms[0], ms[1]);
#pragma unroll
      for (int nf = 0; nf < 4; ++nf) {
        int rr = nf * 32 + l31;
        short8 bf = *(const short8*)(&wt[rr * 256 + (((kd * 2 + hi) ^ (rr & 31)) * 8)]);
        acc[nf] = mfma32(af, bf, acc[nf]);
      }
    }
    // D: row = d (A), col = e (B); store HTb[d][e] row-major
#pragma unroll
    for (int nf = 0; nf < 4; ++nf) {
      int e = col0 + nf * 32 + l31;
#pragma unroll
      for (int rr = 0; rr < 16; ++rr) {
        int d = wrow0 + (rr & 3) + 8 * (rr >> 2) + 4 * hi;
        HTb[(size_t)d * CH + e] = f2bf(acc[nf][rr]);
      }
    }
  } else if (b < 7) {
    // vector: out[c] = W[c]·sx + L*bias[c]
    const float* W  = (b == 4) ? Wq : ((b == 5) ? Wk : Wv);
    const float* bb = (b == 4) ? bq : ((b == 5) ? bk : bv);
    float* outv     = (b == 4) ? sq : ((b == 5) ? sk : cv);
    __shared__ float sxl[256];
    sxl[tid] = sx[tid];
    __syncthreads();
    float s = 0.f;
#pragma unroll
    for (int e = 0; e < 256; e += 8) {
      const float4* w4 = (const float4*)(W + (size_t)tid * CH + e);
      float4 a = w4[0], c = w4[1];
      s += a.x * sxl[e] + a.y * sxl[e + 1] + a.z * sxl[e + 2] + a.w * sxl[e + 3];
      s += c.x * sxl[e + 4] + c.y * sxl[e + 5] + c.z * sxl[e + 6] + c.w * sxl[e + 7];
    }
    outv[tid] = s + 8192.0f * bb[tid];
  } else {
    // r[d] = MT[d]·bq
    __shared__ float bql[256];
    bql[tid] = bq[tid];
    __syncthreads();
    float s = 0.f;
#pragma unroll
    for (int c = 0; c < 256; c += 8) {
      const float4* m4 = (const float4*)(MT + (size_t)tid * CH + c);
      float4 a = m4[0], d4 = m4[1];
      s += a.x * bql[c] + a.y * bql[c + 1] + a.z * bql[c + 2] + a.w * bql[c + 3];
      s += d4.x * bql[c + 4] + d4.y * bql[c + 5] + d4.z * bql[c + 6] + d4.w * bql[c + 7];
    }
    r[tid] = s;
  }
}

// ---------------------------------------------------------------------------
// final: out[i][d] = (cv[d] + ((xb·HT^T)[i][d] + r[d])/L) / (L^2 + sq·sk/L)
// B tile = HTb rows staged via gload16.
// ---------------------------------------------------------------------------
__global__ __launch_bounds__(256) void final_kernel(
    const short* __restrict__ xb, const short* __restrict__ HTb,
    const float* __restrict__ sq, const float* __restrict__ sk,
    const float* __restrict__ cv, const float* __restrict__ r,
    float* __restrict__ out)
{
  __shared__ __align__(16) short wt[128 * 256];   // 64KB
  __shared__ float zs[256];

  const int tid = threadIdx.x;
  zs[tid] = sq[tid] * sk[tid];
  __syncthreads();
#pragma unroll
  for (int st = 128; st > 0; st >>= 1) {
    if (tid < st) zs[tid] += zs[tid + st];
    __syncthreads();
  }
  const float Zinv = 1.0f / (67108864.0f + zs[0] * (1.0f / 8192.0f));

  const int rb = blockIdx.x >> 1, cb = blockIdx.x & 1;
  const int row0 = rb * 128, col0 = cb * 128;
  const int wid = tid >> 6, lane = tid & 63;
  const int l31 = lane & 31, hi = lane >> 5;

#pragma unroll
  for (int i = 0; i < 16; ++i) {
    int g = i * 256 + tid, rr = g >> 5, p = g & 31;
    gload16(HTb + (size_t)(col0 + rr) * CH + (p ^ (rr & 31)) * 8,
            &wt[(i * 256 + wid * 64) * 8]);
  }
  __syncthreads();

  const int wrow0 = row0 + wid * 32;
  f32x16 acc[4] = {};
#pragma unroll
  for (int kd = 0; kd < 16; ++kd) {
    short8 af = *(const short8*)(xb + (size_t)(wrow0 + l31) * CH + kd * 16 + hi * 8);
#pragma unroll
    for (int nf = 0; nf < 4; ++nf) {
      int rr = nf * 32 + l31;
      short8 bf = *(const short8*)(&wt[rr * 256 + (((kd * 2 + hi) ^ (rr & 31)) * 8)]);
      acc[nf] = mfma32(af, bf, acc[nf]);
    }
  }

#pragma unroll
  for (int nf = 0; nf < 4; ++nf) {
    int d = col0 + nf * 32 + l31;
    float cvd = cv[d], rd = r[d];
#pragma unroll
    for (int rr = 0; rr < 16; ++rr) {
      int row = wrow0 + (rr & 3) + 8 * (rr >> 2) + 4 * hi;
      out[(size_t)row * CH + d] = (cvd + (acc[nf][rr] + rd) * (1.0f / 8192.0f)) * Zinv;
    }
  }
}

// ---------------------------------------------------------------------------
extern "C" void kernel_launch(void* const* d_in, const int* in_sizes, int n_in,
                              void* d_out, int out_size, void* d_ws, size_t ws_size,
                              hipStream_t stream) {
  const float* x  = (const float*)d_in[0];
  const float* Wq = (const float*)d_in[1];
  const float* bq = (const float*)d_in[2];
  const float* Wk = (const float*)d_in[3];
  const float* bk = (const float*)d_in[4];
  const float* Wv = (const float*)d_in[5];
  const float* bv = (const float*)d_in[6];
  float* out = (float*)d_out;

  // ws: xb(4MB) | KT(4MB) | VT(4MB) | Wkb(128K) | Wvb(128K) | HTb(128K)
  //   | MT(256K fp32) | sx | sq | sk | cv | r  (1KB each)
  char* ws = (char*)d_ws;
  short* xb  = (short*)ws;
  short* KTb = xb  + (size_t)LSEQ * CH;
  short* VTb = KTb + (size_t)CH * LSEQ;
  short* Wkb = VTb + (size_t)CH * LSEQ;
  short* Wvb = Wkb + (size_t)CH * CH;
  short* HTb = Wvb + (size_t)CH * CH;
  float* MT  = (float*)(HTb + (size_t)CH * CH);
  float* sx  = MT + (size_t)CH * CH;
  float* sq  = sx + CH;
  float* sk  = sq + CH;
  float* cv  = sk + CH;
  float* r   = cv + CH;

  // zero MT (gram atomics) + sx (prep atomics) — contiguous
  hipMemsetAsync(MT, 0, ((size_t)CH * CH + CH) * sizeof(float), stream);

  prep_kernel<<<130, 256, 0, stream>>>(x, Wk, Wv, xb, Wkb, Wvb, sx);
  kv_kernel<<<dim3(128, 2), 256, 0, stream>>>(xb, Wkb, Wvb, bk, bv, KTb, VTb);
  gram_kernel<<<128, 256, 0, stream>>>(VTb, KTb, MT);
  small_kernel<<<8, 256, 0, stream>>>(MT, Wq, Wk, Wv, bq, bk, bv, sx,
                                      HTb, sq, sk, cv, r);
  final_kernel<<<128, 256, 0, stream>>>(xb, HTb, sq, sk, cv, r, out);
}